// Round 1
// baseline (221.800 us; speedup 1.0000x reference)
//
#include <hip/hip_runtime.h>

#define BATCH 256
#define SEQ   2048
#define NC    32
#define EMB   2048

typedef unsigned short ushort_t;
using f32x4  = __attribute__((ext_vector_type(4))) float;
using bf16x8 = __attribute__((ext_vector_type(8))) short;

using u32_gl = __attribute__((address_space(1))) const unsigned int;
using u32_ld = __attribute__((address_space(3))) unsigned int;

__device__ __forceinline__ unsigned short f2bf(float f) {
  unsigned int u = __float_as_uint(f);
  u += 0x7FFFu + ((u >> 16) & 1u);   // round-to-nearest-even (finite inputs)
  return (unsigned short)(u >> 16);
}

// ---------------------------------------------------------------------------
// x: (B, S, C) f32  ->  xT: (C, B, S) bf16
// Block: one (b, 64-s) tile; read 64x32 f32 contiguous, LDS-transpose, write
// 16B bf16 chunks along s (coalesced in 128B segments).
// ---------------------------------------------------------------------------
__global__ __launch_bounds__(256) void transpose_x_kernel(
    const float* __restrict__ x, ushort_t* __restrict__ xT) {
  __shared__ float tile[64][33];
  const int b  = blockIdx.x >> 5;   // 0..255
  const int st = blockIdx.x & 31;   // s0 = st*64
  const int t  = threadIdx.x;
  const float* src = x + ((size_t)b * SEQ + (size_t)st * 64) * NC;
#pragma unroll
  for (int i = 0; i < 2; ++i) {
    int idx = t + i * 256;          // float4 index, 512 total
    float4 v = reinterpret_cast<const float4*>(src)[idx];
    int s = idx >> 3;               // 8 float4 per 32-c row
    int c = (idx & 7) * 4;
    tile[s][c + 0] = v.x; tile[s][c + 1] = v.y;
    tile[s][c + 2] = v.z; tile[s][c + 3] = v.w;
  }
  __syncthreads();
  const int c  = t >> 3;            // 0..31
  const int si = (t & 7) * 8;       // 0..56
  unsigned int q[4];
#pragma unroll
  for (int p = 0; p < 4; ++p) {
    unsigned int h0 = f2bf(tile[si + 2 * p + 0][c]);
    unsigned int h1 = f2bf(tile[si + 2 * p + 1][c]);
    q[p] = h0 | (h1 << 16);
  }
  ushort_t* dst = xT + (size_t)c * (BATCH * SEQ) + (size_t)b * SEQ + st * 64 + si;
  *reinterpret_cast<uint4*>(dst) = make_uint4(q[0], q[1], q[2], q[3]);
}

// ---------------------------------------------------------------------------
// Grouped GEMM: per block, one channel c, 128x128 output tile, BK=64.
// A: xT[c] (b x s) bf16  -> LDS [128][64], XOR-swizzled (byte ^= (row&7)<<4)
//    staged via global_load_lds(16B) with pre-swizzled global source.
// B: W[c]  (s x e) f32   -> convert bf16, LDS transposed Bt[e][s], same swizzle.
// MFMA 16x16x32 bf16; 4 waves, each 64x64 = 4x4 fragments.
// Epilogue: + bias, ReLU, fp32 stores.
// AMODE==1: fallback without workspace (strided scalar x loads).
// ---------------------------------------------------------------------------
template <int AMODE>
__global__ __launch_bounds__(256, 2) void grouped_gemm_kernel(
    const ushort_t* __restrict__ xT,  // (C,B,S) bf16 (AMODE==0)
    const float* __restrict__ x,      // (B,S,C) f32  (AMODE==1)
    const float* __restrict__ W,      // (C,S,E) f32
    const float* __restrict__ bias,   // (C,E) f32
    float* __restrict__ out) {        // (B,C,E) f32
  __shared__ ushort_t Alds[128 * 64];  // 16 KB
  __shared__ ushort_t Blds[128 * 64];  // 16 KB (Bt layout: [e][s])

  const int bid = blockIdx.x;
  const int c   = bid >> 5;          // 32 blocks per channel (L2/LLC locality)
  const int et  = (bid >> 1) & 15;
  const int bt  = bid & 1;
  const int b0  = bt * 128;
  const int e0  = et * 128;

  const int t    = threadIdx.x;
  const int w    = t >> 6;
  const int wr   = w >> 1;           // wave row (0..1)
  const int wc   = w & 1;            // wave col (0..1)
  const int lane = t & 63;
  const int g    = lane >> 4;        // k-group 0..3
  const int lm   = lane & 15;

  const float* Wc = W + (size_t)c * SEQ * EMB;
  const ushort_t* xTc = xT + (size_t)c * (BATCH * SEQ);

  // B staging mapping: thread covers 8 s-rows x 4 e-cols
  const int srow8 = t >> 5;          // 0..7  -> s-slot
  const int e4    = t & 31;          // 0..31 -> e block of 4

  f32x4 acc[4][4];
#pragma unroll
  for (int i = 0; i < 4; ++i)
#pragma unroll
    for (int j = 0; j < 4; ++j) acc[i][j] = (f32x4){0.f, 0.f, 0.f, 0.f};

  for (int s0 = 0; s0 < SEQ; s0 += 64) {
    // ---- stage A tile (128 b-rows x 64 s) ----
    if (AMODE == 0) {
#pragma unroll
      for (int i = 0; i < 4; ++i) {
        int ch   = i * 256 + t;                 // 16B chunk id, 1024 total
        int m    = ch >> 3;                     // row 0..127
        int slot = (ch & 7) ^ (m & 7);          // inverse-swizzled source slot
        const ushort_t* src = xTc + (size_t)(b0 + m) * SEQ + s0 + slot * 8;
        __builtin_amdgcn_global_load_lds(
            (u32_gl*)src,
            (u32_ld*)((char*)&Alds[0] + ch * 16), 16, 0, 0);
      }
    } else {
#pragma unroll
      for (int i = 0; i < 4; ++i) {
        int ch   = i * 256 + t;
        int m    = ch >> 3;
        int slot = (ch & 7) ^ (m & 7);
        const float* src = x + (size_t)(b0 + m) * (SEQ * NC)
                             + (size_t)(s0 + slot * 8) * NC + c;
        unsigned int q[4];
#pragma unroll
        for (int p = 0; p < 4; ++p) {
          unsigned int h0 = f2bf(src[(2 * p + 0) * NC]);
          unsigned int h1 = f2bf(src[(2 * p + 1) * NC]);
          q[p] = h0 | (h1 << 16);
        }
        *reinterpret_cast<uint4*>((char*)&Alds[0] + ch * 16) =
            make_uint4(q[0], q[1], q[2], q[3]);
      }
    }

    // ---- stage B tile (64 s x 128 e) -> Bt[e][s] bf16, swizzled ----
    {
      const float* wp = Wc + (size_t)(s0 + srow8 * 8) * EMB + e0 + e4 * 4;
      f32x4 wv[8];
#pragma unroll
      for (int r = 0; r < 8; ++r)
        wv[r] = *reinterpret_cast<const f32x4*>(wp + (size_t)r * EMB);
#pragma unroll
      for (int i = 0; i < 4; ++i) {
        const int e_local = e4 * 4 + i;
        unsigned int q0 = (unsigned)f2bf(wv[0][i]) | ((unsigned)f2bf(wv[1][i]) << 16);
        unsigned int q1 = (unsigned)f2bf(wv[2][i]) | ((unsigned)f2bf(wv[3][i]) << 16);
        unsigned int q2 = (unsigned)f2bf(wv[4][i]) | ((unsigned)f2bf(wv[5][i]) << 16);
        unsigned int q3 = (unsigned)f2bf(wv[6][i]) | ((unsigned)f2bf(wv[7][i]) << 16);
        int byte = (e_local * 128 + srow8 * 16) ^ ((e_local & 7) << 4);
        *reinterpret_cast<uint4*>((char*)&Blds[0] + byte) =
            make_uint4(q0, q1, q2, q3);
      }
    }

    __syncthreads();  // drains vmcnt (global_load_lds) + lgkmcnt

    // ---- compute: 2 k-steps of 32 ----
#pragma unroll
    for (int ks = 0; ks < 2; ++ks) {
      bf16x8 af[4], bf[4];
#pragma unroll
      for (int mi = 0; mi < 4; ++mi) {
        int m_local = wr * 64 + mi * 16 + lm;
        int byte = (m_local * 128 + (ks * 4 + g) * 16) ^ ((m_local & 7) << 4);
        af[mi] = *reinterpret_cast<const bf16x8*>((const char*)&Alds[0] + byte);
      }
#pragma unroll
      for (int ni = 0; ni < 4; ++ni) {
        int e_local = wc * 64 + ni * 16 + lm;
        int byte = (e_local * 128 + (ks * 4 + g) * 16) ^ ((e_local & 7) << 4);
        bf[ni] = *reinterpret_cast<const bf16x8*>((const char*)&Blds[0] + byte);
      }
#pragma unroll
      for (int mi = 0; mi < 4; ++mi)
#pragma unroll
        for (int ni = 0; ni < 4; ++ni)
          acc[mi][ni] = __builtin_amdgcn_mfma_f32_16x16x32_bf16(
              af[mi], bf[ni], acc[mi][ni], 0, 0, 0);
    }

    __syncthreads();  // protect LDS before next stage
  }

  // ---- epilogue: bias + ReLU; D layout: col=lane&15, row=(lane>>4)*4+reg ----
  const float* bc = bias + (size_t)c * EMB;
#pragma unroll
  for (int ni = 0; ni < 4; ++ni) {
    const int e = e0 + wc * 64 + ni * 16 + lm;
    const float bv = bc[e];
#pragma unroll
    for (int mi = 0; mi < 4; ++mi) {
      f32x4 a = acc[mi][ni];
      const int mbase = b0 + wr * 64 + mi * 16 + g * 4;
#pragma unroll
      for (int r = 0; r < 4; ++r) {
        float v = a[r] + bv;
        v = fmaxf(v, 0.f);
        out[((size_t)(mbase + r) * NC + c) * EMB + e] = v;
      }
    }
  }
}

extern "C" void kernel_launch(void* const* d_in, const int* in_sizes, int n_in,
                              void* d_out, int out_size, void* d_ws, size_t ws_size,
                              hipStream_t stream) {
  const float* x    = (const float*)d_in[0];   // (256, 2048, 32) f32
  const float* W    = (const float*)d_in[1];   // (32, 2048, 2048) f32
  const float* bias = (const float*)d_in[2];   // (32, 2048) f32
  float* out        = (float*)d_out;           // (256, 32, 2048) f32

  const size_t xT_bytes = (size_t)NC * BATCH * SEQ * sizeof(ushort_t); // 33.5 MB

  if (ws_size >= xT_bytes) {
    ushort_t* xT = (ushort_t*)d_ws;
    transpose_x_kernel<<<BATCH * (SEQ / 64), 256, 0, stream>>>(x, xT);
    grouped_gemm_kernel<0><<<NC * 2 * (EMB / 128), 256, 0, stream>>>(
        xT, x, W, bias, out);
  } else {
    grouped_gemm_kernel<1><<<NC * 2 * (EMB / 128), 256, 0, stream>>>(
        nullptr, x, W, bias, out);
  }
}

// Round 2
// 182.215 us; speedup vs baseline: 1.2172x; 1.2172x over previous
//
#include <hip/hip_runtime.h>

#define BATCH 256
#define SEQ   2048
#define NC    32
#define EMB   2048
#define NT    32          // SEQ / BK, BK = 64

typedef unsigned short ushort_t;
using f32x4  = __attribute__((ext_vector_type(4))) float;
using bf16x8 = __attribute__((ext_vector_type(8))) short;

using u32_gl = __attribute__((address_space(1))) const unsigned int;
using u32_ld = __attribute__((address_space(3))) unsigned int;

__device__ __forceinline__ unsigned short f2bf(float f) {
  unsigned int u = __float_as_uint(f);
  u += 0x7FFFu + ((u >> 16) & 1u);   // RNE (finite inputs)
  return (unsigned short)(u >> 16);
}

// ---------------------------------------------------------------------------
// x: (B, S, C) f32  ->  xT: (C, B, S) bf16
// ---------------------------------------------------------------------------
__global__ __launch_bounds__(256) void transpose_x_kernel(
    const float* __restrict__ x, ushort_t* __restrict__ xT) {
  __shared__ float tile[64][33];
  const int b  = blockIdx.x >> 5;
  const int st = blockIdx.x & 31;
  const int t  = threadIdx.x;
  const float* src = x + ((size_t)b * SEQ + (size_t)st * 64) * NC;
#pragma unroll
  for (int i = 0; i < 2; ++i) {
    int idx = t + i * 256;
    float4 v = reinterpret_cast<const float4*>(src)[idx];
    int s = idx >> 3;
    int c = (idx & 7) * 4;
    tile[s][c + 0] = v.x; tile[s][c + 1] = v.y;
    tile[s][c + 2] = v.z; tile[s][c + 3] = v.w;
  }
  __syncthreads();
  const int c  = t >> 3;
  const int si = (t & 7) * 8;
  unsigned int q[4];
#pragma unroll
  for (int p = 0; p < 4; ++p) {
    unsigned int h0 = f2bf(tile[si + 2 * p + 0][c]);
    unsigned int h1 = f2bf(tile[si + 2 * p + 1][c]);
    q[p] = h0 | (h1 << 16);
  }
  ushort_t* dst = xT + (size_t)c * (BATCH * SEQ) + (size_t)b * SEQ + st * 64 + si;
  *reinterpret_cast<uint4*>(dst) = make_uint4(q[0], q[1], q[2], q[3]);
}

// ---------------------------------------------------------------------------
// Pipelined grouped GEMM (T3+T4: counted vmcnt, dbuf LDS, 2 barriers/iter).
// Per block: one channel c, 128x128 output tile, BK=64, 4 waves (2x2 of 64x64).
// A: xT bf16, global_load_lds(16B), pre-swizzled source, swizzled reads.
// B: W f32 reg-staged (double reg set), convert bf16, ds_write Bt[e][s] swz.
// ---------------------------------------------------------------------------
template <int P>
__device__ __forceinline__ void gemm_iter(
    int t, const ushort_t* __restrict__ xTc, const float* __restrict__ Wc,
    char* AldsB, char* BldsB, f32x4 (&wv)[2][8], f32x4 (&acc)[4][4],
    int tid, int wr, int wc, int g, int lm, int b0, int e0) {
  const int srow8 = tid >> 5;          // 0..7
  const int e4    = tid & 31;          // 0..31

  // ---- step 1: W(t) regs ready (A(t) still in flight: 4 outstanding) ----
  asm volatile("s_waitcnt vmcnt(4)" ::: "memory");
#pragma unroll
  for (int i = 0; i < 4; ++i) {
    const int e_local = e4 * 4 + i;
    unsigned int q0 = (unsigned)f2bf(wv[P][0][i]) | ((unsigned)f2bf(wv[P][1][i]) << 16);
    unsigned int q1 = (unsigned)f2bf(wv[P][2][i]) | ((unsigned)f2bf(wv[P][3][i]) << 16);
    unsigned int q2 = (unsigned)f2bf(wv[P][4][i]) | ((unsigned)f2bf(wv[P][5][i]) << 16);
    unsigned int q3 = (unsigned)f2bf(wv[P][6][i]) | ((unsigned)f2bf(wv[P][7][i]) << 16);
    int byte = (e_local * 128 + srow8 * 16) ^ ((e_local & 7) << 4);
    *reinterpret_cast<uint4*>(BldsB + P * 16384 + byte) = make_uint4(q0, q1, q2, q3);
  }

  // ---- step 2: issue W(t+1) into the other reg set ----
  {
    const int tn = (t + 1) & (NT - 1);
    const float* wp = Wc + (size_t)(tn * 64 + srow8 * 8) * EMB + e0 + e4 * 4;
#pragma unroll
    for (int r = 0; r < 8; ++r)
      wv[P ^ 1][r] = *reinterpret_cast<const f32x4*>(wp + (size_t)r * EMB);
  }

  // ---- step 3: B(t) writes visible; prev-iter compute done everywhere ----
  asm volatile("s_waitcnt lgkmcnt(0)" ::: "memory");
  __builtin_amdgcn_s_barrier();

  // ---- step 4: stage A(t+1) into the other LDS buffer ----
  {
    const int s0n = ((t + 1) & (NT - 1)) * 64;
#pragma unroll
    for (int i = 0; i < 4; ++i) {
      int ch   = i * 256 + tid;               // 16B chunk, 1024 total
      int m    = ch >> 3;                     // row 0..127
      int slot = (ch & 7) ^ (m & 7);          // inverse-swizzled source
      const ushort_t* src = xTc + (size_t)(b0 + m) * SEQ + s0n + slot * 8;
      __builtin_amdgcn_global_load_lds(
          (u32_gl*)src, (u32_ld*)(AldsB + (P ^ 1) * 16384 + ch * 16), 16, 0, 0);
    }
  }

  // ---- step 5: drain own A(t); leave W(t+1)+A(t+1)=12 in flight ----
  asm volatile("s_waitcnt vmcnt(12)" ::: "memory");
  __builtin_amdgcn_sched_barrier(0);

  // ---- step 6: all waves' A(t) complete before anyone reads ----
  __builtin_amdgcn_s_barrier();

  // ---- step 7: compute from parity-P buffers ----
#pragma unroll
  for (int ks = 0; ks < 2; ++ks) {
    bf16x8 af[4], bfr[4];
#pragma unroll
    for (int mi = 0; mi < 4; ++mi) {
      int m_local = wr * 64 + mi * 16 + lm;
      int byte = (m_local * 128 + (ks * 4 + g) * 16) ^ ((m_local & 7) << 4);
      af[mi] = *reinterpret_cast<const bf16x8*>(AldsB + P * 16384 + byte);
    }
#pragma unroll
    for (int ni = 0; ni < 4; ++ni) {
      int e_local = wc * 64 + ni * 16 + lm;
      int byte = (e_local * 128 + (ks * 4 + g) * 16) ^ ((e_local & 7) << 4);
      bfr[ni] = *reinterpret_cast<const bf16x8*>(BldsB + P * 16384 + byte);
    }
#pragma unroll
    for (int mi = 0; mi < 4; ++mi)
#pragma unroll
      for (int ni = 0; ni < 4; ++ni)
        acc[mi][ni] = __builtin_amdgcn_mfma_f32_16x16x32_bf16(
            af[mi], bfr[ni], acc[mi][ni], 0, 0, 0);
  }
}

__global__ __launch_bounds__(256, 2) void grouped_gemm_pipe(
    const ushort_t* __restrict__ xT,  // (C,B,S) bf16
    const float* __restrict__ W,      // (C,S,E) f32
    const float* __restrict__ bias,   // (C,E) f32
    float* __restrict__ out) {        // (B,C,E) f32
  __shared__ ushort_t Alds[2][128 * 64];   // 32 KB
  __shared__ ushort_t Blds[2][128 * 64];   // 32 KB

  // XCD-chunked bijective swizzle: nwg = 1024, 8 XCDs, 128 blocks each.
  const int nwg = NC * 2 * (EMB / 128);
  const int bid = (blockIdx.x % 8) * (nwg / 8) + blockIdx.x / 8;
  const int c   = bid >> 5;
  const int et  = (bid >> 1) & 15;
  const int bt  = bid & 1;
  const int b0  = bt * 128;
  const int e0  = et * 128;

  const int tid  = threadIdx.x;
  const int w    = tid >> 6;
  const int wr   = w >> 1;
  const int wc   = w & 1;
  const int lane = tid & 63;
  const int g    = lane >> 4;
  const int lm   = lane & 15;

  const float* Wc = W + (size_t)c * SEQ * EMB;
  const ushort_t* xTc = xT + (size_t)c * (BATCH * SEQ);
  char* AldsB = (char*)&Alds[0][0];
  char* BldsB = (char*)&Blds[0][0];

  f32x4 wv[2][8];
  f32x4 acc[4][4];
#pragma unroll
  for (int i = 0; i < 4; ++i)
#pragma unroll
    for (int j = 0; j < 4; ++j) acc[i][j] = (f32x4){0.f, 0.f, 0.f, 0.f};

  // ---- prologue: issue W(0) (8 loads), then gl_lds A(0) (4 loads) ----
  {
    const int srow8 = tid >> 5;
    const int e4    = tid & 31;
    const float* wp = Wc + (size_t)(srow8 * 8) * EMB + e0 + e4 * 4;
#pragma unroll
    for (int r = 0; r < 8; ++r)
      wv[0][r] = *reinterpret_cast<const f32x4*>(wp + (size_t)r * EMB);
#pragma unroll
    for (int i = 0; i < 4; ++i) {
      int ch   = i * 256 + tid;
      int m    = ch >> 3;
      int slot = (ch & 7) ^ (m & 7);
      const ushort_t* src = xTc + (size_t)(b0 + m) * SEQ + slot * 8;
      __builtin_amdgcn_global_load_lds(
          (u32_gl*)src, (u32_ld*)(AldsB + ch * 16), 16, 0, 0);
    }
  }

  // ---- main loop, unroll-by-2 for compile-time parity ----
  for (int t = 0; t < NT; t += 2) {
    gemm_iter<0>(t,     xTc, Wc, AldsB, BldsB, wv, acc, tid, wr, wc, g, lm, b0, e0);
    gemm_iter<1>(t + 1, xTc, Wc, AldsB, BldsB, wv, acc, tid, wr, wc, g, lm, b0, e0);
  }

  // drain wrapped prefetch before LDS retire / epilogue
  asm volatile("s_waitcnt vmcnt(0)" ::: "memory");

  // ---- epilogue: bias + ReLU; D: col=lane&15, row=(lane>>4)*4+reg ----
  const float* bc = bias + (size_t)c * EMB;
#pragma unroll
  for (int ni = 0; ni < 4; ++ni) {
    const int e = e0 + wc * 64 + ni * 16 + lm;
    const float bv = bc[e];
#pragma unroll
    for (int mi = 0; mi < 4; ++mi) {
      f32x4 a = acc[mi][ni];
      const int mbase = b0 + wr * 64 + mi * 16 + g * 4;
#pragma unroll
      for (int r = 0; r < 4; ++r) {
        float v = a[r] + bv;
        v = fmaxf(v, 0.f);
        out[((size_t)(mbase + r) * NC + c) * EMB + e] = v;
      }
    }
  }
}

// ---------------------------------------------------------------------------
// Fallback (no workspace): round-1 style, A loaded strided from x directly.
// ---------------------------------------------------------------------------
__global__ __launch_bounds__(256, 2) void grouped_gemm_fallback(
    const float* __restrict__ x, const float* __restrict__ W,
    const float* __restrict__ bias, float* __restrict__ out) {
  __shared__ ushort_t Alds[128 * 64];
  __shared__ ushort_t Blds[128 * 64];
  const int bid = blockIdx.x;
  const int c   = bid >> 5;
  const int et  = (bid >> 1) & 15;
  const int bt  = bid & 1;
  const int b0  = bt * 128;
  const int e0  = et * 128;
  const int tid  = threadIdx.x;
  const int w    = tid >> 6;
  const int wr   = w >> 1;
  const int wc   = w & 1;
  const int lane = tid & 63;
  const int g    = lane >> 4;
  const int lm   = lane & 15;
  const float* Wc = W + (size_t)c * SEQ * EMB;
  const int srow8 = tid >> 5;
  const int e4    = tid & 31;
  f32x4 acc[4][4];
#pragma unroll
  for (int i = 0; i < 4; ++i)
#pragma unroll
    for (int j = 0; j < 4; ++j) acc[i][j] = (f32x4){0.f, 0.f, 0.f, 0.f};
  for (int s0 = 0; s0 < SEQ; s0 += 64) {
#pragma unroll
    for (int i = 0; i < 4; ++i) {
      int ch   = i * 256 + tid;
      int m    = ch >> 3;
      int slot = (ch & 7) ^ (m & 7);
      const float* src = x + (size_t)(b0 + m) * (SEQ * NC)
                           + (size_t)(s0 + slot * 8) * NC + c;
      unsigned int q[4];
#pragma unroll
      for (int p = 0; p < 4; ++p) {
        unsigned int h0 = f2bf(src[(2 * p + 0) * NC]);
        unsigned int h1 = f2bf(src[(2 * p + 1) * NC]);
        q[p] = h0 | (h1 << 16);
      }
      *reinterpret_cast<uint4*>((char*)&Alds[0] + ch * 16) =
          make_uint4(q[0], q[1], q[2], q[3]);
    }
    {
      const float* wp = Wc + (size_t)(s0 + srow8 * 8) * EMB + e0 + e4 * 4;
      f32x4 wvv[8];
#pragma unroll
      for (int r = 0; r < 8; ++r)
        wvv[r] = *reinterpret_cast<const f32x4*>(wp + (size_t)r * EMB);
#pragma unroll
      for (int i = 0; i < 4; ++i) {
        const int e_local = e4 * 4 + i;
        unsigned int q0 = (unsigned)f2bf(wvv[0][i]) | ((unsigned)f2bf(wvv[1][i]) << 16);
        unsigned int q1 = (unsigned)f2bf(wvv[2][i]) | ((unsigned)f2bf(wvv[3][i]) << 16);
        unsigned int q2 = (unsigned)f2bf(wvv[4][i]) | ((unsigned)f2bf(wvv[5][i]) << 16);
        unsigned int q3 = (unsigned)f2bf(wvv[6][i]) | ((unsigned)f2bf(wvv[7][i]) << 16);
        int byte = (e_local * 128 + srow8 * 16) ^ ((e_local & 7) << 4);
        *reinterpret_cast<uint4*>((char*)&Blds[0] + byte) =
            make_uint4(q0, q1, q2, q3);
      }
    }
    __syncthreads();
#pragma unroll
    for (int ks = 0; ks < 2; ++ks) {
      bf16x8 af[4], bfr[4];
#pragma unroll
      for (int mi = 0; mi < 4; ++mi) {
        int m_local = wr * 64 + mi * 16 + lm;
        int byte = (m_local * 128 + (ks * 4 + g) * 16) ^ ((m_local & 7) << 4);
        af[mi] = *reinterpret_cast<const bf16x8*>((const char*)&Alds[0] + byte);
      }
#pragma unroll
      for (int ni = 0; ni < 4; ++ni) {
        int e_local = wc * 64 + ni * 16 + lm;
        int byte = (e_local * 128 + (ks * 4 + g) * 16) ^ ((e_local & 7) << 4);
        bfr[ni] = *reinterpret_cast<const bf16x8*>((const char*)&Blds[0] + byte);
      }
#pragma unroll
      for (int mi = 0; mi < 4; ++mi)
#pragma unroll
        for (int ni = 0; ni < 4; ++ni)
          acc[mi][ni] = __builtin_amdgcn_mfma_f32_16x16x32_bf16(
              af[mi], bfr[ni], acc[mi][ni], 0, 0, 0);
    }
    __syncthreads();
  }
  const float* bc = bias + (size_t)c * EMB;
#pragma unroll
  for (int ni = 0; ni < 4; ++ni) {
    const int e = e0 + wc * 64 + ni * 16 + lm;
    const float bv = bc[e];
#pragma unroll
    for (int mi = 0; mi < 4; ++mi) {
      f32x4 a = acc[mi][ni];
      const int mbase = b0 + wr * 64 + mi * 16 + g * 4;
#pragma unroll
      for (int r = 0; r < 4; ++r) {
        float v = a[r] + bv;
        v = fmaxf(v, 0.f);
        out[((size_t)(mbase + r) * NC + c) * EMB + e] = v;
      }
    }
  }
}

extern "C" void kernel_launch(void* const* d_in, const int* in_sizes, int n_in,
                              void* d_out, int out_size, void* d_ws, size_t ws_size,
                              hipStream_t stream) {
  const float* x    = (const float*)d_in[0];
  const float* W    = (const float*)d_in[1];
  const float* bias = (const float*)d_in[2];
  float* out        = (float*)d_out;

  const size_t xT_bytes = (size_t)NC * BATCH * SEQ * sizeof(ushort_t);

  if (ws_size >= xT_bytes) {
    ushort_t* xT = (ushort_t*)d_ws;
    transpose_x_kernel<<<BATCH * (SEQ / 64), 256, 0, stream>>>(x, xT);
    grouped_gemm_pipe<<<NC * 2 * (EMB / 128), 256, 0, stream>>>(xT, W, bias, out);
  } else {
    grouped_gemm_fallback<<<NC * 2 * (EMB / 128), 256, 0, stream>>>(x, W, bias, out);
  }
}

// Round 3
// 158.540 us; speedup vs baseline: 1.3990x; 1.1493x over previous
//
#include <hip/hip_runtime.h>

#define BATCH 256
#define SEQ   2048
#define NC    32
#define EMB   2048
#define NT    32          // SEQ / BK, BK = 64

typedef unsigned short ushort_t;
using f32x4  = __attribute__((ext_vector_type(4))) float;
using bf16x8 = __attribute__((ext_vector_type(8))) short;

using u32_gl = __attribute__((address_space(1))) const unsigned int;
using u32_ld = __attribute__((address_space(3))) unsigned int;

__device__ __forceinline__ unsigned short f2bf(float f) {
  unsigned int u = __float_as_uint(f);
  u += 0x7FFFu + ((u >> 16) & 1u);   // RNE (finite inputs)
  return (unsigned short)(u >> 16);
}

// ---------------------------------------------------------------------------
// x: (B, S, C) f32  ->  xT: (C, B, S) bf16
// ---------------------------------------------------------------------------
__global__ __launch_bounds__(256) void transpose_x_kernel(
    const float* __restrict__ x, ushort_t* __restrict__ xT) {
  __shared__ float tile[64][33];
  const int b  = blockIdx.x >> 5;
  const int st = blockIdx.x & 31;
  const int t  = threadIdx.x;
  const float* src = x + ((size_t)b * SEQ + (size_t)st * 64) * NC;
#pragma unroll
  for (int i = 0; i < 2; ++i) {
    int idx = t + i * 256;
    float4 v = reinterpret_cast<const float4*>(src)[idx];
    int s = idx >> 3;
    int c = (idx & 7) * 4;
    tile[s][c + 0] = v.x; tile[s][c + 1] = v.y;
    tile[s][c + 2] = v.z; tile[s][c + 3] = v.w;
  }
  __syncthreads();
  const int c  = t >> 3;
  const int si = (t & 7) * 8;
  unsigned int q[4];
#pragma unroll
  for (int p = 0; p < 4; ++p) {
    unsigned int h0 = f2bf(tile[si + 2 * p + 0][c]);
    unsigned int h1 = f2bf(tile[si + 2 * p + 1][c]);
    q[p] = h0 | (h1 << 16);
  }
  ushort_t* dst = xT + (size_t)c * (BATCH * SEQ) + (size_t)b * SEQ + st * 64 + si;
  *reinterpret_cast<uint4*>(dst) = make_uint4(q[0], q[1], q[2], q[3]);
}

// ---------------------------------------------------------------------------
// BM=256 pipelined grouped GEMM: each block owns one (c, 128-e) tile across
// ALL of B=256 -> every W element is read by exactly ONE block (no HBM
// double-fetch risk). 512 threads = 8 waves (4x2 grid of 64x64 tiles).
// LDS 96 KB (A dbuf 64 KB + B dbuf 32 KB) -> 1 block/CU; counted vmcnt keeps
// W/A streams in flight across both barriers (T3+T4).
// ---------------------------------------------------------------------------
template <int P>
__device__ __forceinline__ void gemm_iter(
    int t, const ushort_t* __restrict__ xTc, const float* __restrict__ Wc,
    char* AldsB, char* BldsB, f32x4 (&wv)[2][4], f32x4 (&acc)[4][4],
    int tid, int wr, int wc, int g, int lm, int e0) {
  const int srow4 = tid >> 5;          // 0..15 -> s rows srow4*4 .. +3
  const int e4    = tid & 31;          // 0..31 -> e block of 4

  // ---- step 1: W(t) regs ready (A(t) still in flight: 4 outstanding) ----
  asm volatile("s_waitcnt vmcnt(4)" ::: "memory");
#pragma unroll
  for (int i = 0; i < 4; ++i) {
    const int e_local = e4 * 4 + i;
    unsigned int q0 = (unsigned)f2bf(wv[P][0][i]) | ((unsigned)f2bf(wv[P][1][i]) << 16);
    unsigned int q1 = (unsigned)f2bf(wv[P][2][i]) | ((unsigned)f2bf(wv[P][3][i]) << 16);
    int byte = (e_local * 128 + srow4 * 8) ^ ((e_local & 7) << 4);
    *reinterpret_cast<uint2*>(BldsB + P * 16384 + byte) = make_uint2(q0, q1);
  }

  // ---- step 2: issue W(t+1) (4 loads) into the other reg set ----
  {
    const int tn = (t + 1) & (NT - 1);
    const float* wp = Wc + (size_t)(tn * 64 + srow4 * 4) * EMB + e0 + e4 * 4;
#pragma unroll
    for (int r = 0; r < 4; ++r)
      wv[P ^ 1][r] = *reinterpret_cast<const f32x4*>(wp + (size_t)r * EMB);
  }

  // ---- step 3: B(t) LDS writes visible ----
  asm volatile("s_waitcnt lgkmcnt(0)" ::: "memory");
  __builtin_amdgcn_s_barrier();

  // ---- step 4: stage A(t+1) (256x64 bf16, 4 gl_lds/thread) ----
  {
    const int s0n = ((t + 1) & (NT - 1)) * 64;
#pragma unroll
    for (int i = 0; i < 4; ++i) {
      int ch   = i * 512 + tid;               // 16B chunk, 2048 total
      int m    = ch >> 3;                     // row 0..255
      int slot = (ch & 7) ^ (m & 7);          // inverse-swizzled source
      const ushort_t* src = xTc + (size_t)m * SEQ + s0n + slot * 8;
      __builtin_amdgcn_global_load_lds(
          (u32_gl*)src, (u32_ld*)(AldsB + (P ^ 1) * 32768 + ch * 16), 16, 0, 0);
    }
  }

  // ---- step 5: drain own A(t); leave W(t+1)+A(t+1)=8 in flight ----
  asm volatile("s_waitcnt vmcnt(8)" ::: "memory");
  __builtin_amdgcn_sched_barrier(0);

  // ---- step 6: all waves' A(t) complete before anyone reads ----
  __builtin_amdgcn_s_barrier();

  // ---- step 7: compute from parity-P buffers ----
#pragma unroll
  for (int ks = 0; ks < 2; ++ks) {
    bf16x8 af[4], bfr[4];
#pragma unroll
    for (int mi = 0; mi < 4; ++mi) {
      int m_local = wr * 64 + mi * 16 + lm;
      int byte = (m_local * 128 + (ks * 4 + g) * 16) ^ ((m_local & 7) << 4);
      af[mi] = *reinterpret_cast<const bf16x8*>(AldsB + P * 32768 + byte);
    }
#pragma unroll
    for (int ni = 0; ni < 4; ++ni) {
      int e_local = wc * 64 + ni * 16 + lm;
      int byte = (e_local * 128 + (ks * 4 + g) * 16) ^ ((e_local & 7) << 4);
      bfr[ni] = *reinterpret_cast<const bf16x8*>(BldsB + P * 16384 + byte);
    }
#pragma unroll
    for (int mi = 0; mi < 4; ++mi)
#pragma unroll
      for (int ni = 0; ni < 4; ++ni)
        acc[mi][ni] = __builtin_amdgcn_mfma_f32_16x16x32_bf16(
            af[mi], bfr[ni], acc[mi][ni], 0, 0, 0);
  }
}

__global__ __launch_bounds__(512, 2) void grouped_gemm_pipe(
    const ushort_t* __restrict__ xT,  // (C,B,S) bf16
    const float* __restrict__ W,      // (C,S,E) f32
    const float* __restrict__ bias,   // (C,E) f32
    float* __restrict__ out) {        // (B,C,E) f32
  __shared__ ushort_t Alds[2][256 * 64];   // 64 KB
  __shared__ ushort_t Blds[2][128 * 64];   // 32 KB

  // Bijective XCD-chunked swizzle: nwg = 512, 64 per XCD.
  const int bid = (blockIdx.x & 7) * 64 + (blockIdx.x >> 3);
  const int c   = bid >> 4;          // 0..31
  const int et  = bid & 15;
  const int e0  = et * 128;

  const int tid  = threadIdx.x;
  const int w    = tid >> 6;
  const int wr   = w >> 1;           // 0..3
  const int wc   = w & 1;            // 0..1
  const int lane = tid & 63;
  const int g    = lane >> 4;
  const int lm   = lane & 15;

  const float* Wc = W + (size_t)c * SEQ * EMB;
  const ushort_t* xTc = xT + (size_t)c * (BATCH * SEQ);
  char* AldsB = (char*)&Alds[0][0];
  char* BldsB = (char*)&Blds[0][0];

  f32x4 wv[2][4];
  f32x4 acc[4][4];
#pragma unroll
  for (int i = 0; i < 4; ++i)
#pragma unroll
    for (int j = 0; j < 4; ++j) acc[i][j] = (f32x4){0.f, 0.f, 0.f, 0.f};

  // ---- prologue: issue W(0) (4 loads), then gl_lds A(0) (4 loads) ----
  {
    const int srow4 = tid >> 5;
    const int e4    = tid & 31;
    const float* wp = Wc + (size_t)(srow4 * 4) * EMB + e0 + e4 * 4;
#pragma unroll
    for (int r = 0; r < 4; ++r)
      wv[0][r] = *reinterpret_cast<const f32x4*>(wp + (size_t)r * EMB);
#pragma unroll
    for (int i = 0; i < 4; ++i) {
      int ch   = i * 512 + tid;
      int m    = ch >> 3;
      int slot = (ch & 7) ^ (m & 7);
      const ushort_t* src = xTc + (size_t)m * SEQ + slot * 8;
      __builtin_amdgcn_global_load_lds(
          (u32_gl*)src, (u32_ld*)(AldsB + ch * 16), 16, 0, 0);
    }
  }

  // ---- main loop, unroll-by-2 for compile-time parity ----
  for (int t = 0; t < NT; t += 2) {
    gemm_iter<0>(t,     xTc, Wc, AldsB, BldsB, wv, acc, tid, wr, wc, g, lm, e0);
    gemm_iter<1>(t + 1, xTc, Wc, AldsB, BldsB, wv, acc, tid, wr, wc, g, lm, e0);
  }

  // drain wrapped prefetch before epilogue
  asm volatile("s_waitcnt vmcnt(0)" ::: "memory");

  // ---- epilogue: bias + ReLU; D: col=lane&15, row=(lane>>4)*4+reg ----
  const float* bc = bias + (size_t)c * EMB;
#pragma unroll
  for (int ni = 0; ni < 4; ++ni) {
    const int e = e0 + wc * 64 + ni * 16 + lm;
    const float bv = bc[e];
#pragma unroll
    for (int mi = 0; mi < 4; ++mi) {
      f32x4 a = acc[mi][ni];
      const int mbase = wr * 64 + mi * 16 + g * 4;
#pragma unroll
      for (int r = 0; r < 4; ++r) {
        float v = a[r] + bv;
        v = fmaxf(v, 0.f);
        out[((size_t)(mbase + r) * NC + c) * EMB + e] = v;
      }
    }
  }
}

// ---------------------------------------------------------------------------
// Fallback (no workspace): round-1 style, A loaded strided from x directly.
// ---------------------------------------------------------------------------
__global__ __launch_bounds__(256, 2) void grouped_gemm_fallback(
    const float* __restrict__ x, const float* __restrict__ W,
    const float* __restrict__ bias, float* __restrict__ out) {
  __shared__ ushort_t Alds[128 * 64];
  __shared__ ushort_t Blds[128 * 64];
  const int bid = blockIdx.x;
  const int c   = bid >> 5;
  const int et  = (bid >> 1) & 15;
  const int bt  = bid & 1;
  const int b0  = bt * 128;
  const int e0  = et * 128;
  const int tid  = threadIdx.x;
  const int w    = tid >> 6;
  const int wr   = w >> 1;
  const int wc   = w & 1;
  const int lane = tid & 63;
  const int g    = lane >> 4;
  const int lm   = lane & 15;
  const float* Wc = W + (size_t)c * SEQ * EMB;
  const int srow8 = tid >> 5;
  const int e4    = tid & 31;
  f32x4 acc[4][4];
#pragma unroll
  for (int i = 0; i < 4; ++i)
#pragma unroll
    for (int j = 0; j < 4; ++j) acc[i][j] = (f32x4){0.f, 0.f, 0.f, 0.f};
  for (int s0 = 0; s0 < SEQ; s0 += 64) {
#pragma unroll
    for (int i = 0; i < 4; ++i) {
      int ch   = i * 256 + tid;
      int m    = ch >> 3;
      int slot = (ch & 7) ^ (m & 7);
      const float* src = x + (size_t)(b0 + m) * (SEQ * NC)
                           + (size_t)(s0 + slot * 8) * NC + c;
      unsigned int q[4];
#pragma unroll
      for (int p = 0; p < 4; ++p) {
        unsigned int h0 = f2bf(src[(2 * p + 0) * NC]);
        unsigned int h1 = f2bf(src[(2 * p + 1) * NC]);
        q[p] = h0 | (h1 << 16);
      }
      *reinterpret_cast<uint4*>((char*)&Alds[0] + ch * 16) =
          make_uint4(q[0], q[1], q[2], q[3]);
    }
    {
      const float* wp = Wc + (size_t)(s0 + srow8 * 8) * EMB + e0 + e4 * 4;
      f32x4 wvv[8];
#pragma unroll
      for (int r = 0; r < 8; ++r)
        wvv[r] = *reinterpret_cast<const f32x4*>(wp + (size_t)r * EMB);
#pragma unroll
      for (int i = 0; i < 4; ++i) {
        const int e_local = e4 * 4 + i;
        unsigned int q0 = (unsigned)f2bf(wvv[0][i]) | ((unsigned)f2bf(wvv[1][i]) << 16);
        unsigned int q1 = (unsigned)f2bf(wvv[2][i]) | ((unsigned)f2bf(wvv[3][i]) << 16);
        unsigned int q2 = (unsigned)f2bf(wvv[4][i]) | ((unsigned)f2bf(wvv[5][i]) << 16);
        unsigned int q3 = (unsigned)f2bf(wvv[6][i]) | ((unsigned)f2bf(wvv[7][i]) << 16);
        int byte = (e_local * 128 + srow8 * 16) ^ ((e_local & 7) << 4);
        *reinterpret_cast<uint4*>((char*)&Blds[0] + byte) =
            make_uint4(q0, q1, q2, q3);
      }
    }
    __syncthreads();
#pragma unroll
    for (int ks = 0; ks < 2; ++ks) {
      bf16x8 af[4], bfr[4];
#pragma unroll
      for (int mi = 0; mi < 4; ++mi) {
        int m_local = wr * 64 + mi * 16 + lm;
        int byte = (m_local * 128 + (ks * 4 + g) * 16) ^ ((m_local & 7) << 4);
        af[mi] = *reinterpret_cast<const bf16x8*>((const char*)&Alds[0] + byte);
      }
#pragma unroll
      for (int ni = 0; ni < 4; ++ni) {
        int e_local = wc * 64 + ni * 16 + lm;
        int byte = (e_local * 128 + (ks * 4 + g) * 16) ^ ((e_local & 7) << 4);
        bfr[ni] = *reinterpret_cast<const bf16x8*>((const char*)&Blds[0] + byte);
      }
#pragma unroll
      for (int mi = 0; mi < 4; ++mi)
#pragma unroll
        for (int ni = 0; ni < 4; ++ni)
          acc[mi][ni] = __builtin_amdgcn_mfma_f32_16x16x32_bf16(
              af[mi], bfr[ni], acc[mi][ni], 0, 0, 0);
    }
    __syncthreads();
  }
  const float* bc = bias + (size_t)c * EMB;
#pragma unroll
  for (int ni = 0; ni < 4; ++ni) {
    const int e = e0 + wc * 64 + ni * 16 + lm;
    const float bv = bc[e];
#pragma unroll
    for (int mi = 0; mi < 4; ++mi) {
      f32x4 a = acc[mi][ni];
      const int mbase = b0 + wr * 64 + mi * 16 + g * 4;
#pragma unroll
      for (int r = 0; r < 4; ++r) {
        float v = a[r] + bv;
        v = fmaxf(v, 0.f);
        out[((size_t)(mbase + r) * NC + c) * EMB + e] = v;
      }
    }
  }
}

extern "C" void kernel_launch(void* const* d_in, const int* in_sizes, int n_in,
                              void* d_out, int out_size, void* d_ws, size_t ws_size,
                              hipStream_t stream) {
  const float* x    = (const float*)d_in[0];
  const float* W    = (const float*)d_in[1];
  const float* bias = (const float*)d_in[2];
  float* out        = (float*)d_out;

  const size_t xT_bytes = (size_t)NC * BATCH * SEQ * sizeof(ushort_t);

  if (ws_size >= xT_bytes) {
    ushort_t* xT = (ushort_t*)d_ws;
    transpose_x_kernel<<<BATCH * (SEQ / 64), 256, 0, stream>>>(x, xT);
    grouped_gemm_pipe<<<NC * (EMB / 128), 512, 0, stream>>>(xT, W, bias, out);
  } else {
    grouped_gemm_fallback<<<NC * 2 * (EMB / 128), 256, 0, stream>>>(x, W, bias, out);
  }
}